// Round 12
// baseline (71.407 us; speedup 1.0000x reference)
//
#include <hip/hip_runtime.h>
#include <hip/hip_bf16.h>

#define NN 4096
#define IN_F 128
#define OUT_F 64
#define C_TOT 256
#define ALPHA 0.2f
#define LOG2E 1.4426950408889634f

typedef float f32x4 __attribute__((ext_vector_type(4)));
typedef float f32x2 __attribute__((ext_vector_type(2)));
typedef __bf16 bf16x8 __attribute__((ext_vector_type(8)));

__device__ __forceinline__ unsigned fmap(float f) {
    unsigned u = __float_as_uint(f);
    return (u >> 31) ? ~u : (u | 0x80000000u);
}
__device__ __forceinline__ float funmap(unsigned u) {
    return (u >> 31) ? __uint_as_float(u & 0x7FFFFFFFu) : __uint_as_float(~u);
}
__device__ __forceinline__ unsigned short bfbits(float x) {
    union { __bf16 b; unsigned short u; } t;
    t.b = (__bf16)x;
    return t.u;
}
__device__ __forceinline__ void gl16(const void* g, void* l) {
    __builtin_amdgcn_global_load_lds((const __attribute__((address_space(1))) void*)g,
                                     (__attribute__((address_space(3))) void*)l, 16, 0, 0);
}

// ---------------------------------------------------------------------------
// K1: adj -> PERMUTED bitmask ([row][j4][tile]) via ballot; blocks 0..31 also
// transpose W -> WTbf bf16; block 0 computes uLR=W@a, zeroes Rmax. 1024x256.
// ---------------------------------------------------------------------------
__global__ __launch_bounds__(256) void k_mask(
    const int* __restrict__ adj, unsigned* __restrict__ mask,
    const float* __restrict__ W, const float* __restrict__ a,
    unsigned short* __restrict__ WTbf, float* __restrict__ uLR,
    unsigned int* __restrict__ Rmax)
{
    const int tid = threadIdx.x;
    const int lane = tid & 63, wv = tid >> 6;
    const int row = blockIdx.x * 4 + wv;
    const int* __restrict__ ar = adj + (size_t)row * NN;
    unsigned* __restrict__ mr = mask + (size_t)row * 128;
    for (int c = 0; c < 8; ++c) {
        const int j0 = c * 512;
        unsigned w = 0u;
#pragma unroll
        for (int k = 0; k < 8; ++k) {
            const unsigned long long bb = __ballot(ar[j0 + k * 64 + lane] > 0);
            const unsigned lo = (unsigned)bb, hi = (unsigned)(bb >> 32);
            if ((lane >> 1) == k) w = (lane & 1) ? hi : lo;
        }
        if (lane < 16) {
            const int wi = c * 16 + lane;               // original word index
            mr[(wi & 3) * 32 + (wi >> 2)] = w;          // permuted position
        }
    }

    if (blockIdx.x < 32) {      // merged k_misc
        const int b = blockIdx.x;
        const int c = b * 8 + (tid & 7);
#pragma unroll
        for (int pass = 0; pass < 4; ++pass) {
            const int k = pass * 32 + (tid >> 3);
            WTbf[(size_t)c * IN_F + k] = bfbits(W[k * C_TOT + c]);
        }
        if (b == 0) {
            if (tid < 4) Rmax[tid] = 0u;
            for (int o = tid; o < 1024; o += 256) {
                const int k = o >> 3, j = o & 7;
                const int hd = j & 3, side = j >> 2;
                float s = 0.f;
                for (int f = 0; f < OUT_F; ++f)
                    s = fmaf(W[k * C_TOT + hd * OUT_F + f], a[side * OUT_F + f], s);
                uLR[k * 8 + side * 4 + hd] = s;
            }
        }
    }
}

// ---------------------------------------------------------------------------
// K2: Wh via MFMA -> WhT [256][4096] bf16; f32 left / right*LOG2E; Rmax atomic.
// ---------------------------------------------------------------------------
__global__ __launch_bounds__(256) void k_prep(
    const float* __restrict__ hmat, const unsigned short* __restrict__ WTbf,
    const float* __restrict__ uLR, unsigned short* __restrict__ WhT,
    float* __restrict__ leftT, float* __restrict__ rightT,
    unsigned int* __restrict__ Rmax)
{
    __shared__ float hs[16][132];
    __shared__ float us[128][8];
    const int tid = threadIdx.x;
    const int rowbase = blockIdx.x * 16;

    ((float4*)us)[tid] = ((const float4*)uLR)[tid];
#pragma unroll
    for (int p = 0; p < 8; ++p) {
        const int idx = p * 256 + tid;
        hs[idx >> 7][idx & 127] = hmat[(size_t)rowbase * IN_F + idx];
    }
    __syncthreads();

    const int lane = tid & 63, wv = tid >> 6;
    const int m16 = lane & 15, kg = lane >> 4;

    if (wv == 0) {
        const int row = lane >> 2, hd = lane & 3;
        float aL = 0.f, aR = 0.f;
#pragma unroll
        for (int k = 0; k < 128; k += 4) {
            const float4 hv = *(const float4*)&hs[row][k];
            aL = fmaf(hv.x, us[k][hd],   fmaf(hv.y, us[k+1][hd],   fmaf(hv.z, us[k+2][hd],   fmaf(hv.w, us[k+3][hd],   aL))));
            aR = fmaf(hv.x, us[k][hd+4], fmaf(hv.y, us[k+1][hd+4], fmaf(hv.z, us[k+2][hd+4], fmaf(hv.w, us[k+3][hd+4], aR))));
        }
        leftT [hd * NN + rowbase + row] = aL;
        rightT[hd * NN + rowbase + row] = aR * LOG2E;
        float mx = aR;
#pragma unroll
        for (int s = 4; s < 64; s <<= 1) mx = fmaxf(mx, __shfl_xor(mx, s, 64));
        if (lane < 4) atomicMax(&Rmax[hd], fmap(mx));
    }

    bf16x8 afr[4];
#pragma unroll
    for (int ks = 0; ks < 4; ++ks) {
        const float4 lo = *(const float4*)&hs[m16][ks * 32 + kg * 8];
        const float4 hi = *(const float4*)&hs[m16][ks * 32 + kg * 8 + 4];
        bf16x8 v;
        v[0] = (__bf16)lo.x; v[1] = (__bf16)lo.y; v[2] = (__bf16)lo.z; v[3] = (__bf16)lo.w;
        v[4] = (__bf16)hi.x; v[5] = (__bf16)hi.y; v[6] = (__bf16)hi.z; v[7] = (__bf16)hi.w;
        afr[ks] = v;
    }

#pragma unroll
    for (int nt0 = 0; nt0 < 4; ++nt0) {
        const int col = (wv * 4 + nt0) * 16 + m16;
        f32x4 acc = (f32x4){0.f, 0.f, 0.f, 0.f};
#pragma unroll
        for (int ks = 0; ks < 4; ++ks) {
            union { uint4 u; bf16x8 v; } B;
            B.u = *(const uint4*)(WTbf + (size_t)col * IN_F + ks * 32 + kg * 8);
            acc = __builtin_amdgcn_mfma_f32_16x16x32_bf16(afr[ks], B.v, acc, 0, 0, 0);
        }
#pragma unroll
        for (int i = 0; i < 4; ++i)
            WhT[(size_t)col * NN + rowbase + kg * 4 + i] = bfbits(acc[i]);
    }
}

// ---------------------------------------------------------------------------
// K3: attention + PV. Grid 512 x 512 (block = 32 rows x 1 head).
// R12: 2-buffer stage-AFTER-barrier pipeline, 48KB LDS -> 3 blocks/CU
// (6 waves/SIMD). One raw s_barrier per tile; counted vmcnt(2)/0; WAR-safe
// because compute(t) completes before the end-of-t barrier and STAGE(t+2)
// (same buffer) is issued only after it. Numerics identical to R11.
// ---------------------------------------------------------------------------
__global__ __launch_bounds__(512, 6) void k_attn(
    const unsigned* __restrict__ mask,   // permuted [row][j4][t]
    const unsigned short* __restrict__ WhT,
    const float* __restrict__ leftT,
    const float* __restrict__ rightT,    // pre-scaled by LOG2E
    const unsigned int* __restrict__ Rmax,
    const float* __restrict__ bias,
    float* __restrict__ out)
{
    __shared__ unsigned short Bb[2][64 * 128];   // 32KB (comb overlays)
    __shared__ float rlds[4096];                 // 16KB: this head's rightT

    const int tid = threadIdx.x;
    const int lane = tid & 63;
    const int wv = tid >> 6;        // 0..7
    const int rh = wv & 1;          // row half
    const int j4 = wv >> 1;         // 0..3
    const int rowbase = (blockIdx.x >> 2) * 32;
    const int hd = blockIdx.x & 3;
    const int m = lane & 15;
    const int kg = lane >> 4;
    const int sh = kg * 8;

    // ---- one-time preloads ----
#pragma unroll
    for (int p = 0; p < 2; ++p) {
        const int i = p * 512 + tid;
        *(float4*)&rlds[i * 4] = *(const float4*)(rightT + (size_t)hd * NN + i * 4);
    }
    unsigned mreg[32];
    {
        const unsigned* mrow = mask + (size_t)(rowbase + rh * 16 + m) * 128 + j4 * 32;
#pragma unroll
        for (int p = 0; p < 8; ++p) {
            const uint4 v = *(const uint4*)(mrow + p * 4);
            mreg[p * 4 + 0] = v.x; mreg[p * 4 + 1] = v.y;
            mreg[p * 4 + 2] = v.z; mreg[p * 4 + 3] = v.w;
        }
    }

    // softmax constants (global right-max upper bound)
    const float lf = leftT[hd * NN + rowbase + rh * 16 + m];
    const float rmx = funmap(Rmax[hd]);
    const float x = lf + rmx;
    const float m0v = fmaxf(x, ALPHA * x);
    const float mp0 = m0v * LOG2E;
    const float lf2 = fmaf(lf, LOG2E, -mp0);
    const float qc = -0.8f * mp0;
    const f32x2 lf22 = (f32x2){lf2, lf2};
    const f32x2 al2  = (f32x2){ALPHA, ALPHA};
    const f32x2 qc2  = (f32x2){qc, qc};

    bf16x8 ONE8;
#pragma unroll
    for (int i = 0; i < 8; ++i) ONE8[i] = (__bf16)1.0f;

    // ---- staging geometry (identical to R10/R11) ----
    const int srow0 = wv * 4 + (lane >> 4);
    const int g_lin = lane & 15;
    const int lg = g_lin ^ (srow0 & 15);
    const unsigned short* gsrc0 = WhT + (size_t)(hd * 64 + srow0) * NN + lg * 8;
    const unsigned short* gsrc1 = gsrc0 + (size_t)32 * NN;
    const int d0 = wv * 512 + lane * 8;

#define STAGE(buf, t) {                                  \
    gl16(gsrc0 + (t) * 128, &Bb[buf][d0]);               \
    gl16(gsrc1 + (t) * 128, &Bb[buf][4096 + d0]); }

    const int pg8 = ((j4 * 4 + kg) ^ m) * 8;
    const int bro = m * 128 + pg8;                 // + q*2048

    f32x4 acc0 = (f32x4){0,0,0,0}, acc1 = acc0, acc2 = acc0, acc3 = acc0;
    f32x4 accL = (f32x4){0,0,0,0};                 // denominators via ones-MFMA

    union F4 { f32x4 v; f32x2 h[2]; };

#define COMPUTE(buf, t) {                                                        \
    const unsigned aw = mreg[(t)] >> sh;                                         \
    F4 RA, RB;                                                                   \
    RA.v = *(const f32x4*)&rlds[(t) * 128 + j4 * 32 + sh];                       \
    RB.v = *(const f32x4*)&rlds[(t) * 128 + j4 * 32 + sh + 4];                   \
    const f32x2 rp2[4] = { RA.h[0], RA.h[1], RB.h[0], RB.h[1] };                 \
    union { __bf16 b[8]; bf16x8 v; } Af;                                         \
    _Pragma("unroll")                                                            \
    for (int e = 0; e < 4; ++e) {                                                \
        const f32x2 p = rp2[e] + lf22;                      /* v_pk_add_f32 */   \
        const f32x2 q = __builtin_elementwise_fma(p, al2, qc2); /* v_pk_fma */   \
        const float t0 = fmaxf(p.x, q.x), t1 = fmaxf(p.y, q.y);                  \
        float w0 = exp2f(t0), w1 = exp2f(t1);                                    \
        const unsigned mk0 = (unsigned)(((int)(aw << (31 - 2*e)))     >> 31);    \
        const unsigned mk1 = (unsigned)(((int)(aw << (31 - (2*e+1)))) >> 31);    \
        w0 = __uint_as_float(__float_as_uint(w0) & mk0);                         \
        w1 = __uint_as_float(__float_as_uint(w1) & mk1);                         \
        Af.b[2*e]   = (__bf16)w0;                                                \
        Af.b[2*e+1] = (__bf16)w1;                                                \
    }                                                                            \
    union { uint4 u; bf16x8 v; } B0, B1, B2, B3;                                 \
    B0.u = *(const uint4*)&Bb[buf][bro];                                         \
    B1.u = *(const uint4*)&Bb[buf][bro + 2048];                                  \
    B2.u = *(const uint4*)&Bb[buf][bro + 4096];                                  \
    B3.u = *(const uint4*)&Bb[buf][bro + 6144];                                  \
    acc0 = __builtin_amdgcn_mfma_f32_16x16x32_bf16(Af.v, B0.v, acc0, 0, 0, 0);   \
    acc1 = __builtin_amdgcn_mfma_f32_16x16x32_bf16(Af.v, B1.v, acc1, 0, 0, 0);   \
    acc2 = __builtin_amdgcn_mfma_f32_16x16x32_bf16(Af.v, B2.v, acc2, 0, 0, 0);   \
    acc3 = __builtin_amdgcn_mfma_f32_16x16x32_bf16(Af.v, B3.v, acc3, 0, 0, 0);   \
    accL = __builtin_amdgcn_mfma_f32_16x16x32_bf16(Af.v, ONE8, accL, 0, 0, 0);   \
}

    STAGE(0, 0);
    __syncthreads();   // drains tile-0 DMA + publishes rlds

#pragma unroll
    for (int t = 0; t < 32; ++t) {
        if (t + 1 < 32) {
            STAGE((t + 1) & 1, t + 1);
            asm volatile("s_waitcnt vmcnt(2)" ::: "memory");   // tile t landed
        } else {
            asm volatile("s_waitcnt vmcnt(0)" ::: "memory");
        }
        __builtin_amdgcn_sched_barrier(0);
        COMPUTE(t & 1, t);
        __builtin_amdgcn_sched_barrier(0);
        __builtin_amdgcn_s_barrier();      // all waves done with tile t
    }
#undef STAGE
#undef COMPUTE

    // ---- combine across j-quarters (comb overlays Bb, barrier-separated) ----
    __syncthreads();
    float* comb = (float*)&Bb[0][0];               // [3][2][64][20] = 30.7KB
    if (j4 > 0) {
        float* c = comb + (((j4 - 1) * 2 + rh) * 64 + lane) * 20;
#pragma unroll
        for (int i = 0; i < 4; ++i) {
            c[ 0 + i] = acc0[i]; c[ 4 + i] = acc1[i];
            c[ 8 + i] = acc2[i]; c[12 + i] = acc3[i];
            c[16 + i] = accL[i];
        }
    }
    __syncthreads();
    if (j4 == 0) {
#pragma unroll
        for (int pt = 0; pt < 3; ++pt) {
            const float* c = comb + ((pt * 2 + rh) * 64 + lane) * 20;
#pragma unroll
            for (int i = 0; i < 4; ++i) {
                acc0[i] += c[ 0 + i]; acc1[i] += c[ 4 + i];
                acc2[i] += c[ 8 + i]; acc3[i] += c[12 + i];
                accL[i] += c[16 + i];
            }
        }
#pragma unroll
        for (int q = 0; q < 4; ++q) {
            const f32x4 A = (q == 0) ? acc0 : (q == 1) ? acc1 : (q == 2) ? acc2 : acc3;
            const int col = hd * 64 + q * 16 + m;
            const float bv = bias[col];
#pragma unroll
            for (int i = 0; i < 4; ++i) {
                const int r = kg * 4 + i;
                out[(size_t)(rowbase + rh * 16 + r) * C_TOT + col] = A[i] / accL[i] + bv;
            }
        }
    }
}

extern "C" void kernel_launch(void* const* d_in, const int* in_sizes, int n_in,
                              void* d_out, int out_size, void* d_ws, size_t ws_size,
                              hipStream_t stream) {
    const float* hmat = (const float*)d_in[0];
    const int*   adj  = (const int*)d_in[1];
    const float* W    = (const float*)d_in[2];
    const float* a    = (const float*)d_in[3];
    const float* bias = (const float*)d_in[4];
    float* out = (float*)d_out;

    char* ws = (char*)d_ws;
    unsigned short* WhT  = (unsigned short*)(ws + 0x000000);  // 2MB + pad
    float* rightT        = (float*)(ws + 0x280000);           // 64KB + pad
    float* leftT         = (float*)(ws + 0x2A0000);           // 64KB
    unsigned short* WTbf = (unsigned short*)(ws + 0x2B0000);  // 64KB
    float* uLR           = (float*)(ws + 0x2C0000);           // 4KB
    unsigned int* Rmax   = (unsigned int*)(ws + 0x2C1000);    // 16B
    unsigned* mask       = (unsigned*)(ws + 0x300000);        // 2MB

    hipLaunchKernelGGL(k_mask, dim3(1024), dim3(256), 0, stream,
                       adj, mask, W, a, WTbf, uLR, Rmax);
    hipLaunchKernelGGL(k_prep, dim3(256),  dim3(256), 0, stream,
                       hmat, WTbf, uLR, WhT, leftT, rightT, Rmax);
    hipLaunchKernelGGL(k_attn, dim3(512),  dim3(512), 0, stream,
                       mask, WhT, leftT, rightT, Rmax, bias, out);
}

// Round 13
// 71.336 us; speedup vs baseline: 1.0010x; 1.0010x over previous
//
#include <hip/hip_runtime.h>
#include <hip/hip_bf16.h>

#define NN 4096
#define IN_F 128
#define OUT_F 64
#define C_TOT 256
#define ALPHA 0.2f
#define LOG2E 1.4426950408889634f

typedef float f32x4 __attribute__((ext_vector_type(4)));
typedef float f32x2 __attribute__((ext_vector_type(2)));
typedef __bf16 bf16x8 __attribute__((ext_vector_type(8)));

__device__ __forceinline__ unsigned fmap(float f) {
    unsigned u = __float_as_uint(f);
    return (u >> 31) ? ~u : (u | 0x80000000u);
}
__device__ __forceinline__ float funmap(unsigned u) {
    return (u >> 31) ? __uint_as_float(u & 0x7FFFFFFFu) : __uint_as_float(~u);
}
__device__ __forceinline__ unsigned short bfbits(float x) {
    union { __bf16 b; unsigned short u; } t;
    t.b = (__bf16)x;
    return t.u;
}
__device__ __forceinline__ void gl16(const void* g, void* l) {
    __builtin_amdgcn_global_load_lds((const __attribute__((address_space(1))) void*)g,
                                     (__attribute__((address_space(3))) void*)l, 16, 0, 0);
}

// ---------------------------------------------------------------------------
// K1: adj -> PERMUTED bitmask ([row][j4][jh][t16]) via ballot; blocks 0..31
// also transpose W -> WTbf bf16; block 0 computes uLR=W@a, zeroes Rmax.
// ---------------------------------------------------------------------------
__global__ __launch_bounds__(256) void k_mask(
    const int* __restrict__ adj, unsigned* __restrict__ mask,
    const float* __restrict__ W, const float* __restrict__ a,
    unsigned short* __restrict__ WTbf, float* __restrict__ uLR,
    unsigned int* __restrict__ Rmax)
{
    const int tid = threadIdx.x;
    const int lane = tid & 63, wv = tid >> 6;
    const int row = blockIdx.x * 4 + wv;
    const int* __restrict__ ar = adj + (size_t)row * NN;
    unsigned* __restrict__ mr = mask + (size_t)row * 128;
    for (int c = 0; c < 8; ++c) {
        const int j0 = c * 512;
        unsigned w = 0u;
#pragma unroll
        for (int k = 0; k < 8; ++k) {
            const unsigned long long bb = __ballot(ar[j0 + k * 64 + lane] > 0);
            const unsigned lo = (unsigned)bb, hi = (unsigned)(bb >> 32);
            if ((lane >> 1) == k) w = (lane & 1) ? hi : lo;
        }
        if (lane < 16) {
            const int wi = c * 16 + lane;               // original word index
            mr[(wi & 3) * 32 + (wi >> 2)] = w;          // permuted position
        }
    }

    if (blockIdx.x < 32) {      // merged k_misc
        const int b = blockIdx.x;
        const int c = b * 8 + (tid & 7);
#pragma unroll
        for (int pass = 0; pass < 4; ++pass) {
            const int k = pass * 32 + (tid >> 3);
            WTbf[(size_t)c * IN_F + k] = bfbits(W[k * C_TOT + c]);
        }
        if (b == 0) {
            if (tid < 4) Rmax[tid] = 0u;
            for (int o = tid; o < 1024; o += 256) {
                const int k = o >> 3, j = o & 7;
                const int hd = j & 3, side = j >> 2;
                float s = 0.f;
                for (int f = 0; f < OUT_F; ++f)
                    s = fmaf(W[k * C_TOT + hd * OUT_F + f], a[side * OUT_F + f], s);
                uLR[k * 8 + side * 4 + hd] = s;
            }
        }
    }
}

// ---------------------------------------------------------------------------
// K2: Wh via MFMA -> WhT [256][4096] bf16; f32 left / right*LOG2E; Rmax atomic.
// ---------------------------------------------------------------------------
__global__ __launch_bounds__(256) void k_prep(
    const float* __restrict__ hmat, const unsigned short* __restrict__ WTbf,
    const float* __restrict__ uLR, unsigned short* __restrict__ WhT,
    float* __restrict__ leftT, float* __restrict__ rightT,
    unsigned int* __restrict__ Rmax)
{
    __shared__ float hs[16][132];
    __shared__ float us[128][8];
    const int tid = threadIdx.x;
    const int rowbase = blockIdx.x * 16;

    ((float4*)us)[tid] = ((const float4*)uLR)[tid];
#pragma unroll
    for (int p = 0; p < 8; ++p) {
        const int idx = p * 256 + tid;
        hs[idx >> 7][idx & 127] = hmat[(size_t)rowbase * IN_F + idx];
    }
    __syncthreads();

    const int lane = tid & 63, wv = tid >> 6;
    const int m16 = lane & 15, kg = lane >> 4;

    if (wv == 0) {
        const int row = lane >> 2, hd = lane & 3;
        float aL = 0.f, aR = 0.f;
#pragma unroll
        for (int k = 0; k < 128; k += 4) {
            const float4 hv = *(const float4*)&hs[row][k];
            aL = fmaf(hv.x, us[k][hd],   fmaf(hv.y, us[k+1][hd],   fmaf(hv.z, us[k+2][hd],   fmaf(hv.w, us[k+3][hd],   aL))));
            aR = fmaf(hv.x, us[k][hd+4], fmaf(hv.y, us[k+1][hd+4], fmaf(hv.z, us[k+2][hd+4], fmaf(hv.w, us[k+3][hd+4], aR))));
        }
        leftT [hd * NN + rowbase + row] = aL;
        rightT[hd * NN + rowbase + row] = aR * LOG2E;
        float mx = aR;
#pragma unroll
        for (int s = 4; s < 64; s <<= 1) mx = fmaxf(mx, __shfl_xor(mx, s, 64));
        if (lane < 4) atomicMax(&Rmax[hd], fmap(mx));
    }

    bf16x8 afr[4];
#pragma unroll
    for (int ks = 0; ks < 4; ++ks) {
        const float4 lo = *(const float4*)&hs[m16][ks * 32 + kg * 8];
        const float4 hi = *(const float4*)&hs[m16][ks * 32 + kg * 8 + 4];
        bf16x8 v;
        v[0] = (__bf16)lo.x; v[1] = (__bf16)lo.y; v[2] = (__bf16)lo.z; v[3] = (__bf16)lo.w;
        v[4] = (__bf16)hi.x; v[5] = (__bf16)hi.y; v[6] = (__bf16)hi.z; v[7] = (__bf16)hi.w;
        afr[ks] = v;
    }

#pragma unroll
    for (int nt0 = 0; nt0 < 4; ++nt0) {
        const int col = (wv * 4 + nt0) * 16 + m16;
        f32x4 acc = (f32x4){0.f, 0.f, 0.f, 0.f};
#pragma unroll
        for (int ks = 0; ks < 4; ++ks) {
            union { uint4 u; bf16x8 v; } B;
            B.u = *(const uint4*)(WTbf + (size_t)col * IN_F + ks * 32 + kg * 8);
            acc = __builtin_amdgcn_mfma_f32_16x16x32_bf16(afr[ks], B.v, acc, 0, 0, 0);
        }
#pragma unroll
        for (int i = 0; i < 4; ++i)
            WhT[(size_t)col * NN + rowbase + kg * 4 + i] = bfbits(acc[i]);
    }
}

// ---------------------------------------------------------------------------
// K3: attention partials. Grid 1024 x 512: block = 32 rows x 1 head x j-half
// (2048 cols, 16 tiles of 128). 40KB LDS -> 4 blocks/CU = 32 waves/CU (max).
// Same 2-buffer stage-after-barrier pipeline as R12. Writes PARTIAL numerator
// (jh=0 -> out, jh=1 -> num1 ws) and denominator partials (ones-MFMA) to ws;
// k_fin combines. No divide/bias here.
// ---------------------------------------------------------------------------
__global__ __launch_bounds__(512, 8) void k_attn(
    const unsigned* __restrict__ mask,   // permuted [row][j4][jh][t]
    const unsigned short* __restrict__ WhT,
    const float* __restrict__ leftT,
    const float* __restrict__ rightT,    // pre-scaled by LOG2E
    const unsigned int* __restrict__ Rmax,
    float* __restrict__ out,             // jh=0 numerator partial
    float* __restrict__ num1,            // jh=1 numerator partial
    float* __restrict__ den)             // [2][4][4096]
{
    __shared__ unsigned short Bb[2][64 * 128];   // 32KB (comb overlays)
    __shared__ float rlds[2048];                 // 8KB: this head's j-half

    const int tid = threadIdx.x;
    const int lane = tid & 63;
    const int wv = tid >> 6;        // 0..7
    const int rh = wv & 1;          // row half
    const int j4 = wv >> 1;         // 0..3
    const int jh = blockIdx.x & 1;
    const int hd = (blockIdx.x >> 1) & 3;
    const int rowbase = (blockIdx.x >> 3) * 32;
    const int m = lane & 15;
    const int kg = lane >> 4;
    const int sh = kg * 8;

    // ---- one-time preloads ----
    *(float4*)&rlds[tid * 4] =
        *(const float4*)(rightT + (size_t)hd * NN + jh * 2048 + tid * 4);
    unsigned mreg[16];
    {
        const unsigned* mrow = mask + (size_t)(rowbase + rh * 16 + m) * 128
                               + j4 * 32 + jh * 16;
#pragma unroll
        for (int p = 0; p < 4; ++p) {
            const uint4 v = *(const uint4*)(mrow + p * 4);
            mreg[p * 4 + 0] = v.x; mreg[p * 4 + 1] = v.y;
            mreg[p * 4 + 2] = v.z; mreg[p * 4 + 3] = v.w;
        }
    }

    // softmax constants (global right-max upper bound; additive partials)
    const float lf = leftT[hd * NN + rowbase + rh * 16 + m];
    const float rmx = funmap(Rmax[hd]);
    const float x = lf + rmx;
    const float m0v = fmaxf(x, ALPHA * x);
    const float mp0 = m0v * LOG2E;
    const float lf2 = fmaf(lf, LOG2E, -mp0);
    const float qc = -0.8f * mp0;
    const f32x2 lf22 = (f32x2){lf2, lf2};
    const f32x2 al2  = (f32x2){ALPHA, ALPHA};
    const f32x2 qc2  = (f32x2){qc, qc};

    bf16x8 ONE8;
#pragma unroll
    for (int i = 0; i < 8; ++i) ONE8[i] = (__bf16)1.0f;

    // ---- staging geometry ----
    const int srow0 = wv * 4 + (lane >> 4);
    const int g_lin = lane & 15;
    const int lg = g_lin ^ (srow0 & 15);
    const unsigned short* gsrc0 = WhT + (size_t)(hd * 64 + srow0) * NN
                                  + jh * 2048 + lg * 8;
    const unsigned short* gsrc1 = gsrc0 + (size_t)32 * NN;
    const int d0 = wv * 512 + lane * 8;

#define STAGE(buf, t) {                                  \
    gl16(gsrc0 + (t) * 128, &Bb[buf][d0]);               \
    gl16(gsrc1 + (t) * 128, &Bb[buf][4096 + d0]); }

    const int pg8 = ((j4 * 4 + kg) ^ m) * 8;
    const int bro = m * 128 + pg8;                 // + q*2048

    f32x4 acc0 = (f32x4){0,0,0,0}, acc1 = acc0, acc2 = acc0, acc3 = acc0;
    f32x4 accL = (f32x4){0,0,0,0};                 // denominators via ones-MFMA

    union F4 { f32x4 v; f32x2 h[2]; };

#define COMPUTE(buf, t) {                                                        \
    const unsigned aw = mreg[(t)] >> sh;                                         \
    F4 RA, RB;                                                                   \
    RA.v = *(const f32x4*)&rlds[(t) * 128 + j4 * 32 + sh];                       \
    RB.v = *(const f32x4*)&rlds[(t) * 128 + j4 * 32 + sh + 4];                   \
    const f32x2 rp2[4] = { RA.h[0], RA.h[1], RB.h[0], RB.h[1] };                 \
    union { __bf16 b[8]; bf16x8 v; } Af;                                         \
    _Pragma("unroll")                                                            \
    for (int e = 0; e < 4; ++e) {                                                \
        const f32x2 p = rp2[e] + lf22;                                           \
        const f32x2 q = __builtin_elementwise_fma(p, al2, qc2);                  \
        const float t0 = fmaxf(p.x, q.x), t1 = fmaxf(p.y, q.y);                  \
        float w0 = exp2f(t0), w1 = exp2f(t1);                                    \
        const unsigned mk0 = (unsigned)(((int)(aw << (31 - 2*e)))     >> 31);    \
        const unsigned mk1 = (unsigned)(((int)(aw << (31 - (2*e+1)))) >> 31);    \
        w0 = __uint_as_float(__float_as_uint(w0) & mk0);                         \
        w1 = __uint_as_float(__float_as_uint(w1) & mk1);                         \
        Af.b[2*e]   = (__bf16)w0;                                                \
        Af.b[2*e+1] = (__bf16)w1;                                                \
    }                                                                            \
    union { uint4 u; bf16x8 v; } B0, B1, B2, B3;                                 \
    B0.u = *(const uint4*)&Bb[buf][bro];                                         \
    B1.u = *(const uint4*)&Bb[buf][bro + 2048];                                  \
    B2.u = *(const uint4*)&Bb[buf][bro + 4096];                                  \
    B3.u = *(const uint4*)&Bb[buf][bro + 6144];                                  \
    acc0 = __builtin_amdgcn_mfma_f32_16x16x32_bf16(Af.v, B0.v, acc0, 0, 0, 0);   \
    acc1 = __builtin_amdgcn_mfma_f32_16x16x32_bf16(Af.v, B1.v, acc1, 0, 0, 0);   \
    acc2 = __builtin_amdgcn_mfma_f32_16x16x32_bf16(Af.v, B2.v, acc2, 0, 0, 0);   \
    acc3 = __builtin_amdgcn_mfma_f32_16x16x32_bf16(Af.v, B3.v, acc3, 0, 0, 0);   \
    accL = __builtin_amdgcn_mfma_f32_16x16x32_bf16(Af.v, ONE8, accL, 0, 0, 0);   \
}

    STAGE(0, 0);
    __syncthreads();   // drains tile-0 DMA + publishes rlds

#pragma unroll
    for (int t = 0; t < 16; ++t) {
        if (t + 1 < 16) {
            STAGE((t + 1) & 1, t + 1);
            asm volatile("s_waitcnt vmcnt(2)" ::: "memory");   // tile t landed
        } else {
            asm volatile("s_waitcnt vmcnt(0)" ::: "memory");
        }
        __builtin_amdgcn_sched_barrier(0);
        COMPUTE(t & 1, t);
        __builtin_amdgcn_sched_barrier(0);
        __builtin_amdgcn_s_barrier();      // all waves done with tile t
    }
#undef STAGE
#undef COMPUTE

    // ---- combine across j-quarters (comb overlays Bb, barrier-separated) ----
    __syncthreads();
    float* comb = (float*)&Bb[0][0];               // [3][2][64][20] = 30.7KB
    if (j4 > 0) {
        float* c = comb + (((j4 - 1) * 2 + rh) * 64 + lane) * 20;
#pragma unroll
        for (int i = 0; i < 4; ++i) {
            c[ 0 + i] = acc0[i]; c[ 4 + i] = acc1[i];
            c[ 8 + i] = acc2[i]; c[12 + i] = acc3[i];
            c[16 + i] = accL[i];
        }
    }
    __syncthreads();
    if (j4 == 0) {
#pragma unroll
        for (int pt = 0; pt < 3; ++pt) {
            const float* c = comb + ((pt * 2 + rh) * 64 + lane) * 20;
#pragma unroll
            for (int i = 0; i < 4; ++i) {
                acc0[i] += c[ 0 + i]; acc1[i] += c[ 4 + i];
                acc2[i] += c[ 8 + i]; acc3[i] += c[12 + i];
                accL[i] += c[16 + i];
            }
        }
        float* numdst = jh ? num1 : out;
#pragma unroll
        for (int q = 0; q < 4; ++q) {
            const f32x4 A = (q == 0) ? acc0 : (q == 1) ? acc1 : (q == 2) ? acc2 : acc3;
            const int col = hd * 64 + q * 16 + m;
#pragma unroll
            for (int i = 0; i < 4; ++i) {
                const int r = kg * 4 + i;
                numdst[(size_t)(rowbase + rh * 16 + r) * C_TOT + col] = A[i];
            }
        }
        if (m == 0) {
#pragma unroll
            for (int i = 0; i < 4; ++i)
                den[(size_t)jh * 4 * NN + hd * NN + rowbase + rh * 16 + kg * 4 + i] = accL[i];
        }
    }
}

// ---------------------------------------------------------------------------
// K4: finalize — out = (n0 + n1) / (d0 + d1) + bias. Grid 1024 x 256
// (1 float4 per thread).
// ---------------------------------------------------------------------------
__global__ __launch_bounds__(256) void k_fin(
    float* __restrict__ out, const float* __restrict__ num1,
    const float* __restrict__ den, const float* __restrict__ bias)
{
    const int idx = blockIdx.x * 256 + threadIdx.x;   // float4 index
    const int row = idx >> 6;
    const int c4 = (idx & 63) * 4;
    const int hd = c4 >> 6;
    const float d = den[hd * NN + row] + den[4 * NN + hd * NN + row];
    const float rd = 1.0f / d;
    float4 n0 = *(float4*)(out + (size_t)row * C_TOT + c4);
    const float4 n1 = *(const float4*)(num1 + (size_t)row * C_TOT + c4);
    const float4 bv = *(const float4*)(bias + c4);
    n0.x = fmaf(n0.x + n1.x, rd, bv.x);
    n0.y = fmaf(n0.y + n1.y, rd, bv.y);
    n0.z = fmaf(n0.z + n1.z, rd, bv.z);
    n0.w = fmaf(n0.w + n1.w, rd, bv.w);
    *(float4*)(out + (size_t)row * C_TOT + c4) = n0;
}

extern "C" void kernel_launch(void* const* d_in, const int* in_sizes, int n_in,
                              void* d_out, int out_size, void* d_ws, size_t ws_size,
                              hipStream_t stream) {
    const float* hmat = (const float*)d_in[0];
    const int*   adj  = (const int*)d_in[1];
    const float* W    = (const float*)d_in[2];
    const float* a    = (const float*)d_in[3];
    const float* bias = (const float*)d_in[4];
    float* out = (float*)d_out;

    char* ws = (char*)d_ws;
    unsigned short* WhT  = (unsigned short*)(ws + 0x000000);  // 2MB + pad
    float* rightT        = (float*)(ws + 0x280000);           // 64KB + pad
    float* leftT         = (float*)(ws + 0x2A0000);           // 64KB
    unsigned short* WTbf = (unsigned short*)(ws + 0x2B0000);  // 64KB
    float* uLR           = (float*)(ws + 0x2C0000);           // 4KB
    unsigned int* Rmax   = (unsigned int*)(ws + 0x2C1000);    // 16B
    unsigned* mask       = (unsigned*)(ws + 0x300000);        // 2MB
    float* num1          = (float*)(ws + 0x500000);           // 4MB
    float* den           = (float*)(ws + 0x900000);           // 128KB

    hipLaunchKernelGGL(k_mask, dim3(1024), dim3(256), 0, stream,
                       adj, mask, W, a, WTbf, uLR, Rmax);
    hipLaunchKernelGGL(k_prep, dim3(256),  dim3(256), 0, stream,
                       hmat, WTbf, uLR, WhT, leftT, rightT, Rmax);
    hipLaunchKernelGGL(k_attn, dim3(1024), dim3(512), 0, stream,
                       mask, WhT, leftT, rightT, Rmax, out, num1, den);
    hipLaunchKernelGGL(k_fin,  dim3(1024), dim3(256), 0, stream,
                       out, num1, den, bias);
}

// Round 14
// 64.004 us; speedup vs baseline: 1.1157x; 1.1146x over previous
//
#include <hip/hip_runtime.h>
#include <hip/hip_bf16.h>

#define NN 4096
#define IN_F 128
#define OUT_F 64
#define C_TOT 256
#define ALPHA 0.2f
#define LOG2E 1.4426950408889634f

typedef float f32x4 __attribute__((ext_vector_type(4)));
typedef float f32x2 __attribute__((ext_vector_type(2)));
typedef __bf16 bf16x8 __attribute__((ext_vector_type(8)));

__device__ __forceinline__ unsigned fmap(float f) {
    unsigned u = __float_as_uint(f);
    return (u >> 31) ? ~u : (u | 0x80000000u);
}
__device__ __forceinline__ float funmap(unsigned u) {
    return (u >> 31) ? __uint_as_float(u & 0x7FFFFFFFu) : __uint_as_float(~u);
}
__device__ __forceinline__ unsigned short bfbits(float x) {
    union { __bf16 b; unsigned short u; } t;
    t.b = (__bf16)x;
    return t.u;
}
__device__ __forceinline__ void gl16(const void* g, void* l) {
    __builtin_amdgcn_global_load_lds((const __attribute__((address_space(1))) void*)g,
                                     (__attribute__((address_space(3))) void*)l, 16, 0, 0);
}

// ---------------------------------------------------------------------------
// K1: adj -> PERMUTED bitmask ([row][(wi&3)*32+(wi>>2)]) via ballot; blocks
// 0..31 also transpose W -> WTbf bf16; block 0 computes uLR=W@a, zeroes Rmax.
// ---------------------------------------------------------------------------
__global__ __launch_bounds__(256) void k_mask(
    const int* __restrict__ adj, unsigned* __restrict__ mask,
    const float* __restrict__ W, const float* __restrict__ a,
    unsigned short* __restrict__ WTbf, float* __restrict__ uLR,
    unsigned int* __restrict__ Rmax)
{
    const int tid = threadIdx.x;
    const int lane = tid & 63, wv = tid >> 6;
    const int row = blockIdx.x * 4 + wv;
    const int* __restrict__ ar = adj + (size_t)row * NN;
    unsigned* __restrict__ mr = mask + (size_t)row * 128;
    for (int c = 0; c < 8; ++c) {
        const int j0 = c * 512;
        unsigned w = 0u;
#pragma unroll
        for (int k = 0; k < 8; ++k) {
            const unsigned long long bb = __ballot(ar[j0 + k * 64 + lane] > 0);
            const unsigned lo = (unsigned)bb, hi = (unsigned)(bb >> 32);
            if ((lane >> 1) == k) w = (lane & 1) ? hi : lo;
        }
        if (lane < 16) {
            const int wi = c * 16 + lane;               // original word index
            mr[(wi & 3) * 32 + (wi >> 2)] = w;          // permuted position
        }
    }

    if (blockIdx.x < 32) {      // merged k_misc
        const int b = blockIdx.x;
        const int c = b * 8 + (tid & 7);
#pragma unroll
        for (int pass = 0; pass < 4; ++pass) {
            const int k = pass * 32 + (tid >> 3);
            WTbf[(size_t)c * IN_F + k] = bfbits(W[k * C_TOT + c]);
        }
        if (b == 0) {
            if (tid < 4) Rmax[tid] = 0u;
            for (int o = tid; o < 1024; o += 256) {
                const int k = o >> 3, j = o & 7;
                const int hd = j & 3, side = j >> 2;
                float s = 0.f;
                for (int f = 0; f < OUT_F; ++f)
                    s = fmaf(W[k * C_TOT + hd * OUT_F + f], a[side * OUT_F + f], s);
                uLR[k * 8 + side * 4 + hd] = s;
            }
        }
    }
}

// ---------------------------------------------------------------------------
// K2: Wh via MFMA -> WhT [256][4096] bf16; f32 left / right*LOG2E; Rmax atomic.
// ---------------------------------------------------------------------------
__global__ __launch_bounds__(256) void k_prep(
    const float* __restrict__ hmat, const unsigned short* __restrict__ WTbf,
    const float* __restrict__ uLR, unsigned short* __restrict__ WhT,
    float* __restrict__ leftT, float* __restrict__ rightT,
    unsigned int* __restrict__ Rmax)
{
    __shared__ float hs[16][132];
    __shared__ float us[128][8];
    const int tid = threadIdx.x;
    const int rowbase = blockIdx.x * 16;

    ((float4*)us)[tid] = ((const float4*)uLR)[tid];
#pragma unroll
    for (int p = 0; p < 8; ++p) {
        const int idx = p * 256 + tid;
        hs[idx >> 7][idx & 127] = hmat[(size_t)rowbase * IN_F + idx];
    }
    __syncthreads();

    const int lane = tid & 63, wv = tid >> 6;
    const int m16 = lane & 15, kg = lane >> 4;

    if (wv == 0) {
        const int row = lane >> 2, hd = lane & 3;
        float aL = 0.f, aR = 0.f;
#pragma unroll
        for (int k = 0; k < 128; k += 4) {
            const float4 hv = *(const float4*)&hs[row][k];
            aL = fmaf(hv.x, us[k][hd],   fmaf(hv.y, us[k+1][hd],   fmaf(hv.z, us[k+2][hd],   fmaf(hv.w, us[k+3][hd],   aL))));
            aR = fmaf(hv.x, us[k][hd+4], fmaf(hv.y, us[k+1][hd+4], fmaf(hv.z, us[k+2][hd+4], fmaf(hv.w, us[k+3][hd+4], aR))));
        }
        leftT [hd * NN + rowbase + row] = aL;
        rightT[hd * NN + rowbase + row] = aR * LOG2E;
        float mx = aR;
#pragma unroll
        for (int s = 4; s < 64; s <<= 1) mx = fmaxf(mx, __shfl_xor(mx, s, 64));
        if (lane < 4) atomicMax(&Rmax[hd], fmap(mx));
    }

    bf16x8 afr[4];
#pragma unroll
    for (int ks = 0; ks < 4; ++ks) {
        const float4 lo = *(const float4*)&hs[m16][ks * 32 + kg * 8];
        const float4 hi = *(const float4*)&hs[m16][ks * 32 + kg * 8 + 4];
        bf16x8 v;
        v[0] = (__bf16)lo.x; v[1] = (__bf16)lo.y; v[2] = (__bf16)lo.z; v[3] = (__bf16)lo.w;
        v[4] = (__bf16)hi.x; v[5] = (__bf16)hi.y; v[6] = (__bf16)hi.z; v[7] = (__bf16)hi.w;
        afr[ks] = v;
    }

#pragma unroll
    for (int nt0 = 0; nt0 < 4; ++nt0) {
        const int col = (wv * 4 + nt0) * 16 + m16;
        f32x4 acc = (f32x4){0.f, 0.f, 0.f, 0.f};
#pragma unroll
        for (int ks = 0; ks < 4; ++ks) {
            union { uint4 u; bf16x8 v; } B;
            B.u = *(const uint4*)(WTbf + (size_t)col * IN_F + ks * 32 + kg * 8);
            acc = __builtin_amdgcn_mfma_f32_16x16x32_bf16(afr[ks], B.v, acc, 0, 0, 0);
        }
#pragma unroll
        for (int i = 0; i < 4; ++i)
            WhT[(size_t)col * NN + rowbase + kg * 4 + i] = bfbits(acc[i]);
    }
}

// ---------------------------------------------------------------------------
// K3: attention partials. Grid 512 x 1024: block = 64 rows x 1 head x j-half.
// 16 waves = rowquarter(4) x j4(4); 16 tiles of 128 j. 4 staging buffers,
// depth-3 prefetch, counted vmcnt(2), one barrier/tile ordered
// [vmcnt; barrier; STAGE(t+3); COMPUTE(t)] (WAR-safe). LDS exactly 80KB ->
// 2 blocks/CU = 32 waves/CU. Softmax weights via FACTORED exp + max-trick:
// w = max(EL*ER[j], EL2*ER2[j]) — zero transcendentals in the loop.
// Denominator via ones-MFMA. Partial outputs; k_fin combines.
// ---------------------------------------------------------------------------
__global__ __launch_bounds__(1024, 8) void k_attn(
    const unsigned* __restrict__ mask,   // permuted
    const unsigned short* __restrict__ WhT,
    const float* __restrict__ leftT,
    const float* __restrict__ rightT,    // pre-scaled by LOG2E
    const unsigned int* __restrict__ Rmax,
    float* __restrict__ out,             // jh=0 numerator partial
    float* __restrict__ num1,            // jh=1 numerator partial
    float* __restrict__ den)             // [2][4][4096]
{
    __shared__ unsigned short Bb[4][64 * 128];   // 64KB (comb overlays)
    __shared__ float erl[2048];                  // 8KB: ER = exp2(r)
    __shared__ float er2l[2048];                 // 8KB: ER2 = exp2(0.2 r)

    const int tid = threadIdx.x;
    const int lane = tid & 63;
    const int wvi = tid >> 6;       // 0..15
    const int rh = wvi & 3;         // row quarter (16 rows each)
    const int j4 = wvi >> 2;        // 0..3
    const int jh = blockIdx.x & 1;
    const int hd = (blockIdx.x >> 1) & 3;
    const int rowbase = (blockIdx.x >> 3) * 64;
    const int m = lane & 15;
    const int kg = lane >> 4;
    const int sh = kg * 8;

    // ---- staging geometry: 64 rows x 16 granules, 1 gl16/thread ----
    const int srow = tid >> 4;                  // 0..63
    const int g_lin = tid & 15;
    const int lg = g_lin ^ (srow & 15);         // inverse-swizzled source granule
    const unsigned short* gsrc = WhT + (size_t)(hd * 64 + srow) * NN
                                 + jh * 2048 + lg * 8;
    const int d0 = srow * 128 + g_lin * 8;      // linear dest (shorts)

#define STAGE(buf, t) { gl16(gsrc + (t) * 128, &Bb[buf][d0]); }

    STAGE(0, 0); STAGE(1, 1); STAGE(2, 2);      // depth-3 preload

    // ---- ER/ER2 tables: 2 j per thread ----
    {
        const float2 rv = *(const float2*)(rightT + (size_t)hd * NN + jh * 2048 + tid * 2);
        erl [tid * 2    ] = exp2f(rv.x);
        erl [tid * 2 + 1] = exp2f(rv.y);
        er2l[tid * 2    ] = exp2f(ALPHA * rv.x);
        er2l[tid * 2 + 1] = exp2f(ALPHA * rv.y);
    }

    // ---- mask words -> 16 VGPRs ----
    unsigned mreg[16];
    {
        const unsigned* mrow = mask + (size_t)(rowbase + rh * 16 + m) * 128
                               + j4 * 32 + jh * 16;
#pragma unroll
        for (int p = 0; p < 4; ++p) {
            const uint4 v = *(const uint4*)(mrow + p * 4);
            mreg[p * 4 + 0] = v.x; mreg[p * 4 + 1] = v.y;
            mreg[p * 4 + 2] = v.z; mreg[p * 4 + 3] = v.w;
        }
    }

    // ---- per-lane factored-exp constants ----
    const float lf = leftT[hd * NN + rowbase + rh * 16 + m];
    const float rmx = funmap(Rmax[hd]);
    const float x = lf + rmx;
    const float m0v = fmaxf(x, ALPHA * x);
    const float mp0 = m0v * LOG2E;
    const float EL  = exp2f(fmaf(lf,         LOG2E, -mp0));
    const float EL2 = exp2f(fmaf(lf * ALPHA, LOG2E, -mp0));
    const f32x2 ELv  = (f32x2){EL,  EL};
    const f32x2 EL2v = (f32x2){EL2, EL2};

    bf16x8 ONE8;
#pragma unroll
    for (int i = 0; i < 8; ++i) ONE8[i] = (__bf16)1.0f;

    __syncthreads();   // er tables ready (also drains preload DMAs)

    const int pg8 = ((j4 * 4 + kg) ^ m) * 8;
    const int bro = m * 128 + pg8;                 // + q*2048

    f32x4 acc0 = (f32x4){0,0,0,0}, acc1 = acc0, acc2 = acc0, acc3 = acc0;
    f32x4 accL = (f32x4){0,0,0,0};

    union F4 { f32x4 v; f32x2 h[2]; };

#define COMPUTE(buf, t) {                                                        \
    const unsigned aw = mreg[(t)] >> sh;                                         \
    F4 E0, E1, F0, F1;                                                           \
    E0.v = *(const f32x4*)&erl [(t) * 128 + j4 * 32 + sh];                       \
    E1.v = *(const f32x4*)&erl [(t) * 128 + j4 * 32 + sh + 4];                   \
    F0.v = *(const f32x4*)&er2l[(t) * 128 + j4 * 32 + sh];                       \
    F1.v = *(const f32x4*)&er2l[(t) * 128 + j4 * 32 + sh + 4];                   \
    const f32x2 ep[4] = { E0.h[0], E0.h[1], E1.h[0], E1.h[1] };                  \
    const f32x2 fp[4] = { F0.h[0], F0.h[1], F1.h[0], F1.h[1] };                  \
    union { __bf16 b[8]; bf16x8 v; } Af;                                         \
    _Pragma("unroll")                                                            \
    for (int e = 0; e < 4; ++e) {                                                \
        const f32x2 full = ep[e] * ELv;              /* v_pk_mul_f32 */          \
        const f32x2 leak = fp[e] * EL2v;             /* v_pk_mul_f32 */          \
        float w0 = fmaxf(full.x, leak.x);            /* lrelu via max */         \
        float w1 = fmaxf(full.y, leak.y);                                        \
        const unsigned mk0 = (unsigned)(((int)(aw << (31 - 2*e)))     >> 31);    \
        const unsigned mk1 = (unsigned)(((int)(aw << (31 - (2*e+1)))) >> 31);    \
        w0 = __uint_as_float(__float_as_uint(w0) & mk0);                         \
        w1 = __uint_as_float(__float_as_uint(w1) & mk1);                         \
        Af.b[2*e]   = (__bf16)w0;                                                \
        Af.b[2*e+1] = (__bf16)w1;                                                \
    }                                                                            \
    union { uint4 u; bf16x8 v; } B0, B1, B2, B3;                                 \
    B0.u = *(const uint4*)&Bb[buf][bro];                                         \
    B1.u = *(const uint4*)&Bb[buf][bro + 2048];                                  \
    B2.u = *(const uint4*)&Bb[buf][bro + 4096];                                  \
    B3.u = *(const uint4*)&Bb[buf][bro + 6144];                                  \
    acc0 = __builtin_amdgcn_mfma_f32_16x16x32_bf16(Af.v, B0.v, acc0, 0, 0, 0);   \
    acc1 = __builtin_amdgcn_mfma_f32_16x16x32_bf16(Af.v, B1.v, acc1, 0, 0, 0);   \
    acc2 = __builtin_amdgcn_mfma_f32_16x16x32_bf16(Af.v, B2.v, acc2, 0, 0, 0);   \
    acc3 = __builtin_amdgcn_mfma_f32_16x16x32_bf16(Af.v, B3.v, acc3, 0, 0, 0);   \
    accL = __builtin_amdgcn_mfma_f32_16x16x32_bf16(Af.v, ONE8, accL, 0, 0, 0);   \
}

#pragma unroll
    for (int t = 0; t < 16; ++t) {
        if (t <= 13)      { asm volatile("s_waitcnt vmcnt(2)" ::: "memory"); }
        else if (t == 14) { asm volatile("s_waitcnt vmcnt(1)" ::: "memory"); }
        else              { asm volatile("s_waitcnt vmcnt(0)" ::: "memory"); }
        __builtin_amdgcn_sched_barrier(0);
        __builtin_amdgcn_s_barrier();      // everyone's tile-t landed; prev reads done
        if (t + 3 < 16) STAGE((t + 3) & 3, t + 3);
        COMPUTE(t & 3, t);
        __builtin_amdgcn_sched_barrier(0);
    }
#undef STAGE
#undef COMPUTE

    // ---- combine across j4 (comb overlays Bb, barrier-separated) ----
    __syncthreads();
    float* comb = (float*)&Bb[0][0];               // [3][4][64][20] = 61.4KB
    if (j4 > 0) {
        float* c = comb + (((j4 - 1) * 4 + rh) * 64 + lane) * 20;
#pragma unroll
        for (int i = 0; i < 4; ++i) {
            c[ 0 + i] = acc0[i]; c[ 4 + i] = acc1[i];
            c[ 8 + i] = acc2[i]; c[12 + i] = acc3[i];
            c[16 + i] = accL[i];
        }
    }
    __syncthreads();
    if (j4 == 0) {
#pragma unroll
        for (int pt = 0; pt < 3; ++pt) {
            const float* c = comb + ((pt * 4 + rh) * 64 + lane) * 20;
#pragma unroll
            for (int i = 0; i < 4; ++i) {
                acc0[i] += c[ 0 + i]; acc1[i] += c[ 4 + i];
                acc2[i] += c[ 8 + i]; acc3[i] += c[12 + i];
                accL[i] += c[16 + i];
            }
        }
        float* numdst = jh ? num1 : out;
#pragma unroll
        for (int q = 0; q < 4; ++q) {
            const f32x4 A = (q == 0) ? acc0 : (q == 1) ? acc1 : (q == 2) ? acc2 : acc3;
            const int col = hd * 64 + q * 16 + m;
#pragma unroll
            for (int i = 0; i < 4; ++i) {
                const int r = kg * 4 + i;
                numdst[(size_t)(rowbase + rh * 16 + r) * C_TOT + col] = A[i];
            }
        }
        if (m == 0) {
#pragma unroll
            for (int i = 0; i < 4; ++i)
                den[(size_t)jh * 4 * NN + hd * NN + rowbase + rh * 16 + kg * 4 + i] = accL[i];
        }
    }
}

// ---------------------------------------------------------------------------
// K4: finalize — out = (n0 + n1) / (d0 + d1) + bias. Grid 1024 x 256.
// ---------------------------------------------------------------------------
__global__ __launch_bounds__(256) void k_fin(
    float* __restrict__ out, const float* __restrict__ num1,
    const float* __restrict__ den, const float* __restrict__ bias)
{
    const int idx = blockIdx.x * 256 + threadIdx.x;   // float4 index
    const int row = idx >> 6;
    const int c4 = (idx & 63) * 4;
    const int hd = c4 >> 6;
    const float d = den[hd * NN + row] + den[4 * NN + hd * NN + row];
    const float rd = 1.0f / d;
    float4 n0 = *(float4*)(out + (size_t)row * C_TOT + c4);
    const float4 n1 = *(const float4*)(num1 + (size_t)row * C_TOT + c4);
    const float4 bv = *(const float4*)(bias + c4);
    n0.x = fmaf(n0.x + n1.x, rd, bv.x);
    n0.y = fmaf(n0.y + n1.y, rd, bv.y);
    n0.z = fmaf(n0.z + n1.z, rd, bv.z);
    n0.w = fmaf(n0.w + n1.w, rd, bv.w);
    *(float4*)(out + (size_t)row * C_TOT + c4) = n0;
}

extern "C" void kernel_launch(void* const* d_in, const int* in_sizes, int n_in,
                              void* d_out, int out_size, void* d_ws, size_t ws_size,
                              hipStream_t stream) {
    const float* hmat = (const float*)d_in[0];
    const int*   adj  = (const int*)d_in[1];
    const float* W    = (const float*)d_in[2];
    const float* a    = (const float*)d_in[3];
    const float* bias = (const float*)d_in[4];
    float* out = (float*)d_out;

    char* ws = (char*)d_ws;
    unsigned short* WhT  = (unsigned short*)(ws + 0x000000);  // 2MB + pad
    float* rightT        = (float*)(ws + 0x280000);           // 64KB + pad
    float* leftT         = (float*)(ws + 0x2A0000);           // 64KB
    unsigned short* WTbf = (unsigned short*)(ws + 0x2B0000);  // 64KB
    float* uLR           = (float*)(ws + 0x2C0000);           // 4KB
    unsigned int* Rmax   = (unsigned int*)(ws + 0x2C1000);    // 16B
    unsigned* mask       = (unsigned*)(ws + 0x300000);        // 2MB
    float* num1          = (float*)(ws + 0x500000);           // 4MB
    float* den           = (float*)(ws + 0x900000);           // 128KB

    hipLaunchKernelGGL(k_mask, dim3(1024), dim3(256), 0, stream,
                       adj, mask, W, a, WTbf, uLR, Rmax);
    hipLaunchKernelGGL(k_prep, dim3(256),  dim3(256), 0, stream,
                       hmat, WTbf, uLR, WhT, leftT, rightT, Rmax);
    hipLaunchKernelGGL(k_attn, dim3(512),  dim3(1024), 0, stream,
                       mask, WhT, leftT, rightT, Rmax, out, num1, den);
    hipLaunchKernelGGL(k_fin,  dim3(1024), dim3(256), 0, stream,
                       out, num1, den, bias);
}